// Round 2
// baseline (200.668 us; speedup 1.0000x reference)
//
#include <hip/hip_runtime.h>

// Problem constants (fixed by the reference's setup_inputs).
constexpr int N = 8192;          // row length
constexpr int K = 64;            // top-k
constexpr int THREADS = 512;     // 8 waves/block
constexpr int WAVES = THREADS / 64;
constexpr int EPT = N / THREADS; // 16 elements per thread (in registers)
constexpr int VEC = EPT / 4;     // 4 float4 loads per thread per operand
constexpr int CAP = 3072;        // candidate buffer capacity (12 KB)
constexpr int RPB = 2;           // rows per block -> grid 1024 = 4 blocks/CU x 256 CUs
constexpr int NB = 2048;         // round-1 bins
constexpr int COFF = NB + 4;     // 2nd hist copy offset: +4 words -> bank-skewed
constexpr int HWORDS = 2 * NB + 8;

typedef float f32x4 __attribute__((ext_vector_type(4)));

// Map fp32 bits to an unsigned key with the same total order as float.
__device__ __forceinline__ unsigned orderable(float f) {
    unsigned x = __float_as_uint(f);
    return (x & 0x80000000u) ? ~x : (x | 0x80000000u);
}

// Barrier that does NOT drain vmcnt: prefetched global loads stay in flight
// across LDS-only phases (m194-m201 verified pattern). All our barriers are
// LDS-communication only except the rare tie path (which uses __syncthreads).
__device__ __forceinline__ void barrier_nd() {
    asm volatile("s_waitcnt lgkmcnt(0)" ::: "memory");
    __builtin_amdgcn_s_barrier();
    asm volatile("" ::: "memory");
}

__global__ __launch_bounds__(THREADS, 8)
void gumbel_topk_onehot(const float* __restrict__ logits,
                        const float* __restrict__ noise,
                        float* __restrict__ out)
{
    __shared__ __align__(16) unsigned hist[HWORDS]; // 16.4 KB: two bank-skewed copies
    __shared__ __align__(16) unsigned cand[CAP];    // 12 KB
    __shared__ unsigned wavesum[WAVES];
    __shared__ unsigned ccount;
    __shared__ unsigned sel_bin, sel_kth, sel_cnt;
    __shared__ unsigned r_val, r_take, r_ceq;

    const int tid  = threadIdx.x;
    const int lane = tid & 63;
    const int wave = tid >> 6;
    const long long row0 = (long long)blockIdx.x * RPB;

    // ---- Issue row 0's loads (16 float4, all in flight) ----
    float4 av[VEC], bv[VEC];
    {
        const float4* lrow = (const float4*)(logits + row0 * (long long)N);
        const float4* nrow = (const float4*)(noise  + row0 * (long long)N);
#pragma unroll
        for (int i = 0; i < VEC; ++i) {
            av[i] = lrow[tid + i * THREADS];
            bv[i] = nrow[tid + i * THREADS];
        }
    }

    // suffix scan + bin selection (bpt = bins per thread; DUAL sums both copies)
#define SELECT_BIN(BPT, DUAL)                                                \
    {                                                                        \
        unsigned p = 0;                                                      \
        _Pragma("unroll")                                                    \
        for (int j = 0; j < (BPT); ++j) {                                    \
            unsigned b = tid * (BPT) + j;                                    \
            p += hist[b] + ((DUAL) ? hist[b + COFF] : 0u);                   \
        }                                                                    \
        unsigned s = p;                                                      \
        _Pragma("unroll")                                                    \
        for (int off = 1; off < 64; off <<= 1) {                             \
            unsigned v = __shfl_down(s, off);                                \
            if (lane + off < 64) s += v;                                     \
        }                                                                    \
        if (lane == 0) wavesum[wave] = s;                                    \
        barrier_nd();                                                        \
        unsigned S = s;                                                      \
        _Pragma("unroll")                                                    \
        for (int w = 0; w < WAVES; ++w) if (w > wave) S += wavesum[w];       \
        unsigned Snext = S - p;                                              \
        if (S >= kth && Snext < kth) {                                       \
            unsigned cum = Snext;                                            \
            for (int j = (BPT) - 1; j >= 0; --j) {                           \
                unsigned b = tid * (BPT) + j;                                \
                unsigned c = hist[b] + ((DUAL) ? hist[b + COFF] : 0u);       \
                if (cum + c >= kth) {                                        \
                    sel_bin = b;                                             \
                    sel_kth = kth - cum;                                     \
                    sel_cnt = c;                                             \
                    break;                                                   \
                }                                                            \
                cum += c;                                                    \
            }                                                                \
        }                                                                    \
        barrier_nd();                                                        \
    }

#pragma unroll
    for (int r = 0; r < RPB; ++r) {
        const long long row = row0 + r;

        // ---- Zero hist + ccount (LDS-only; overlaps in-flight loads) ----
        for (int i = tid; i < HWORDS / 4; i += THREADS)
            ((uint4*)hist)[i] = make_uint4(0u, 0u, 0u, 0u);
        if (tid == 0) ccount = 0u;

        // ---- Convert this row's loads to keys; immediately re-issue the
        //      register slots with NEXT row's loads (pipelined prefetch) ----
        unsigned key[EPT];
        const float4* lnext = (const float4*)(logits + (row + 1) * (long long)N);
        const float4* nnext = (const float4*)(noise  + (row + 1) * (long long)N);
#pragma unroll
        for (int i = 0; i < VEC; ++i) {
            float4 a = av[i], b = bv[i];          // vmcnt wait lands here
            if (r + 1 < RPB) {                    // folds at compile time
                av[i] = lnext[tid + i * THREADS];
                bv[i] = nnext[tid + i * THREADS];
            }
            key[4*i+0] = orderable(a.x + b.x);
            key[4*i+1] = orderable(a.y + b.y);
            key[4*i+2] = orderable(a.z + b.z);
            key[4*i+3] = orderable(a.w + b.w);
        }
        barrier_nd();

        // ======== Round 1: histogram over bits [31:21], lane-parity copies ========
        const unsigned hoff = (lane & 1) ? (unsigned)COFF : 0u;
#pragma unroll
        for (int e = 0; e < EPT; ++e)
            atomicAdd(&hist[(key[e] >> 21) + hoff], 1u);
        barrier_nd();

        unsigned kth = K;
        SELECT_BIN(4, 1)
        const unsigned b1   = sel_bin;   // winning 11-bit high field
        const unsigned cnt1 = sel_cnt;   // elements in that bin
        kth = sel_kth;                   // rank within the bin

        // ---- Compact round-1 survivors (low 21 bits) into small buffer ----
#pragma unroll
        for (int e = 0; e < EPT; ++e) {
            if ((key[e] >> 21) == b1) {
                unsigned pos = atomicAdd(&ccount, 1u);
                if (pos < (unsigned)CAP) cand[pos] = key[e] & 0x1FFFFFu;
            }
        }
        barrier_nd();

        unsigned T, take_eq, c_eq;

        if (cnt1 <= (unsigned)THREADS) {
            // ======== Common path: exact rank-count among survivors ========
            // All lanes read cand at the same index -> LDS broadcast (free).
            const bool have = (tid < (int)cnt1);
            const unsigned myv = have ? cand[tid] : 0u;
            unsigned g = 0, eq = 0;
            int j = 0;
            for (; j + 4 <= (int)cnt1; j += 4) {
                uint4 v = ((const uint4*)cand)[j >> 2];   // 16B broadcast read
                g  += (v.x >  myv) + (v.y >  myv) + (v.z >  myv) + (v.w >  myv);
                eq += (v.x == myv) + (v.y == myv) + (v.z == myv) + (v.w == myv);
            }
            for (; j < (int)cnt1; ++j) {
                unsigned v = cand[j];
                g += (v > myv); eq += (v == myv);
            }
            if (have && g < kth && g + eq >= kth) {
                r_val  = myv;
                r_take = kth - g;   // how many ==T values belong to top-K
                r_ceq  = eq;        // total ==T values
            }
            barrier_nd();
            T       = (b1 << 21) | r_val;
            take_eq = r_take;
            c_eq    = r_ceq;
        } else {
            // ======== Rare fallback: radix rounds 2+3 (single hist copy) ========
            const bool use_cand = (cnt1 <= (unsigned)CAP);

            ((uint4*)hist)[tid] = make_uint4(0u, 0u, 0u, 0u);   // first 2048 bins
            barrier_nd();
            if (use_cand) {
                for (int i = tid; i < (int)cnt1; i += THREADS)
                    atomicAdd(&hist[cand[i] >> 10], 1u);
            } else {
#pragma unroll
                for (int e = 0; e < EPT; ++e)
                    if ((key[e] >> 21) == b1)
                        atomicAdd(&hist[(key[e] >> 10) & 0x7FFu], 1u);
            }
            barrier_nd();

            SELECT_BIN(4, 0)
            const unsigned b2 = sel_bin;
            kth = sel_kth;
            barrier_nd();

            if (tid < 256) ((uint4*)hist)[tid] = make_uint4(0u, 0u, 0u, 0u); // 1024 bins
            barrier_nd();
            if (use_cand) {
                for (int i = tid; i < (int)cnt1; i += THREADS) {
                    unsigned cv = cand[i];
                    if ((cv >> 10) == b2) atomicAdd(&hist[cv & 0x3FFu], 1u);
                }
            } else {
                const unsigned pfx = (b1 << 11) | b2;
#pragma unroll
                for (int e = 0; e < EPT; ++e)
                    if ((key[e] >> 10) == pfx)
                        atomicAdd(&hist[key[e] & 0x3FFu], 1u);
            }
            barrier_nd();

            SELECT_BIN(2, 0)
            T       = (b1 << 21) | (b2 << 10) | sel_bin;
            take_eq = sel_kth;
            c_eq    = sel_cnt;
        }

        const bool fast = (take_eq == c_eq);    // no boundary-straddling tie

        // ---- Write one-hot output from registers (non-temporal) ----
        f32x4* orow = (f32x4*)(out + row * (long long)N);
#pragma unroll
        for (int i = 0; i < VEC; ++i) {
            int idx = tid + i * THREADS;
            f32x4 o;
            o.x = (key[4*i+0] > T || (fast && key[4*i+0] == T)) ? 1.0f : 0.0f;
            o.y = (key[4*i+1] > T || (fast && key[4*i+1] == T)) ? 1.0f : 0.0f;
            o.z = (key[4*i+2] > T || (fast && key[4*i+2] == T)) ? 1.0f : 0.0f;
            o.w = (key[4*i+3] > T || (fast && key[4*i+3] == T)) ? 1.0f : 0.0f;
            __builtin_nontemporal_store(o, &orow[idx]);
        }

        // Rare path: tie group straddles the boundary — lowest indices win
        // (jax.lax.top_k semantics). Recompute serially from global.
        if (!fast) {
            __syncthreads();   // full drain: one-hot stores done before rewrite
            if (tid == 0) {
                const float* lf = logits + row * (long long)N;
                const float* nf = noise  + row * (long long)N;
                float* of = out + row * (long long)N;
                unsigned c = 0;
                for (int i = 0; i < N; ++i) {
                    if (orderable(lf[i] + nf[i]) == T) {
                        of[i] = 1.0f;
                        if (++c == take_eq) break;
                    }
                }
            }
        }
    }
#undef SELECT_BIN
}

extern "C" void kernel_launch(void* const* d_in, const int* in_sizes, int n_in,
                              void* d_out, int out_size, void* d_ws, size_t ws_size,
                              hipStream_t stream) {
    const float* logits = (const float*)d_in[0];
    const float* noise  = (const float*)d_in[1];
    float* out = (float*)d_out;
    const int rows = in_sizes[0] / N;           // 2048
    gumbel_topk_onehot<<<rows / RPB, THREADS, 0, stream>>>(logits, noise, out);
}

// Round 3
// 179.498 us; speedup vs baseline: 1.1179x; 1.1179x over previous
//
#include <hip/hip_runtime.h>

// Problem constants (fixed by the reference's setup_inputs).
constexpr int N = 8192;          // row length
constexpr int K = 64;            // top-k
constexpr int THREADS = 512;     // 8 waves/block
constexpr int WAVES = THREADS / 64;
constexpr int EPT = N / THREADS; // 16 elements per thread (in registers)
constexpr int VEC = EPT / 4;     // 4 float4 loads per thread per operand
constexpr int CAP = 3072;        // candidate buffer capacity (12 KB)
constexpr int RPB = 2;           // rows per block -> grid 1024
constexpr int NB = 2048;         // round-1 bins
constexpr int COFF = NB + 4;     // 2nd hist copy offset: +4 words -> bank-skewed
constexpr int HWORDS = 2 * NB + 8;

typedef float f32x4 __attribute__((ext_vector_type(4)));

// Map fp32 bits to an unsigned key with the same total order as float.
__device__ __forceinline__ unsigned orderable(float f) {
    unsigned x = __float_as_uint(f);
    return (x & 0x80000000u) ? ~x : (x | 0x80000000u);
}

// Barrier that does NOT drain vmcnt: prefetched global loads stay in flight
// across LDS-only phases. All barriers here are LDS-communication only except
// the rare tie path (which uses __syncthreads).
__device__ __forceinline__ void barrier_nd() {
    asm volatile("s_waitcnt lgkmcnt(0)" ::: "memory");
    __builtin_amdgcn_s_barrier();
    asm volatile("" ::: "memory");
}

// launch_bounds(512,4): 128-VGPR budget. (512,8) capped at 64 VGPRs and
// spilled the RPB=2 prefetch state to scratch (+60MB WRITE_SIZE, round 2).
__global__ __launch_bounds__(THREADS, 4)
void gumbel_topk_onehot(const float* __restrict__ logits,
                        const float* __restrict__ noise,
                        float* __restrict__ out)
{
    __shared__ __align__(16) unsigned hist[HWORDS]; // 16.4 KB: two bank-skewed copies
    __shared__ __align__(16) unsigned cand[CAP];    // 12 KB
    __shared__ unsigned wavesum[WAVES];
    __shared__ unsigned ccount;
    __shared__ unsigned sel_bin, sel_kth, sel_cnt;
    __shared__ unsigned r_val, r_take, r_ceq;

    const int tid  = threadIdx.x;
    const int lane = tid & 63;
    const int wave = tid >> 6;
    const long long row0 = (long long)blockIdx.x * RPB;

    // ---- Issue row 0's loads (16 float4, all in flight) ----
    float4 av[VEC], bv[VEC];
    {
        const float4* lrow = (const float4*)(logits + row0 * (long long)N);
        const float4* nrow = (const float4*)(noise  + row0 * (long long)N);
#pragma unroll
        for (int i = 0; i < VEC; ++i) {
            av[i] = lrow[tid + i * THREADS];
            bv[i] = nrow[tid + i * THREADS];
        }
    }

    // suffix scan + bin selection (bpt = bins per thread; DUAL sums both copies)
#define SELECT_BIN(BPT, DUAL)                                                \
    {                                                                        \
        unsigned p = 0;                                                      \
        _Pragma("unroll")                                                    \
        for (int j = 0; j < (BPT); ++j) {                                    \
            unsigned b = tid * (BPT) + j;                                    \
            p += hist[b] + ((DUAL) ? hist[b + COFF] : 0u);                   \
        }                                                                    \
        unsigned s = p;                                                      \
        _Pragma("unroll")                                                    \
        for (int off = 1; off < 64; off <<= 1) {                             \
            unsigned v = __shfl_down(s, off);                                \
            if (lane + off < 64) s += v;                                     \
        }                                                                    \
        if (lane == 0) wavesum[wave] = s;                                    \
        barrier_nd();                                                        \
        unsigned S = s;                                                      \
        _Pragma("unroll")                                                    \
        for (int w = 0; w < WAVES; ++w) if (w > wave) S += wavesum[w];       \
        unsigned Snext = S - p;                                              \
        if (S >= kth && Snext < kth) {                                       \
            unsigned cum = Snext;                                            \
            for (int j = (BPT) - 1; j >= 0; --j) {                           \
                unsigned b = tid * (BPT) + j;                                \
                unsigned c = hist[b] + ((DUAL) ? hist[b + COFF] : 0u);       \
                if (cum + c >= kth) {                                        \
                    sel_bin = b;                                             \
                    sel_kth = kth - cum;                                     \
                    sel_cnt = c;                                             \
                    break;                                                   \
                }                                                            \
                cum += c;                                                    \
            }                                                                \
        }                                                                    \
        barrier_nd();                                                        \
    }

#pragma unroll
    for (int r = 0; r < RPB; ++r) {
        const long long row = row0 + r;

        // ---- Zero hist + ccount (LDS-only; overlaps in-flight loads) ----
        for (int i = tid; i < HWORDS / 4; i += THREADS)
            ((uint4*)hist)[i] = make_uint4(0u, 0u, 0u, 0u);
        if (tid == 0) ccount = 0u;

        // ---- Convert this row's loads to keys; immediately re-issue the
        //      register slots with NEXT row's loads (pipelined prefetch) ----
        unsigned key[EPT];
        const float4* lnext = (const float4*)(logits + (row + 1) * (long long)N);
        const float4* nnext = (const float4*)(noise  + (row + 1) * (long long)N);
#pragma unroll
        for (int i = 0; i < VEC; ++i) {
            float4 a = av[i], b = bv[i];          // vmcnt wait lands here
            if (r + 1 < RPB) {                    // folds at compile time
                av[i] = lnext[tid + i * THREADS];
                bv[i] = nnext[tid + i * THREADS];
            }
            key[4*i+0] = orderable(a.x + b.x);
            key[4*i+1] = orderable(a.y + b.y);
            key[4*i+2] = orderable(a.z + b.z);
            key[4*i+3] = orderable(a.w + b.w);
        }
        barrier_nd();

        // ======== Round 1: histogram over bits [31:21], lane-parity copies ========
        const unsigned hoff = (lane & 1) ? (unsigned)COFF : 0u;
#pragma unroll
        for (int e = 0; e < EPT; ++e)
            atomicAdd(&hist[(key[e] >> 21) + hoff], 1u);
        barrier_nd();

        unsigned kth = K;
        SELECT_BIN(4, 1)
        const unsigned b1   = sel_bin;   // winning 11-bit high field
        const unsigned cnt1 = sel_cnt;   // elements in that bin
        kth = sel_kth;                   // rank within the bin

        // ---- Compact round-1 survivors (low 21 bits) into small buffer ----
#pragma unroll
        for (int e = 0; e < EPT; ++e) {
            if ((key[e] >> 21) == b1) {
                unsigned pos = atomicAdd(&ccount, 1u);
                if (pos < (unsigned)CAP) cand[pos] = key[e] & 0x1FFFFFu;
            }
        }
        barrier_nd();

        unsigned T, take_eq, c_eq;

        if (cnt1 <= (unsigned)THREADS) {
            // ======== Common path: exact rank-count among survivors ========
            // All lanes read cand at the same index -> LDS broadcast (free).
            const bool have = (tid < (int)cnt1);
            const unsigned myv = have ? cand[tid] : 0u;
            unsigned g = 0, eq = 0;
            int j = 0;
            for (; j + 4 <= (int)cnt1; j += 4) {
                uint4 v = ((const uint4*)cand)[j >> 2];   // 16B broadcast read
                g  += (v.x >  myv) + (v.y >  myv) + (v.z >  myv) + (v.w >  myv);
                eq += (v.x == myv) + (v.y == myv) + (v.z == myv) + (v.w == myv);
            }
            for (; j < (int)cnt1; ++j) {
                unsigned v = cand[j];
                g += (v > myv); eq += (v == myv);
            }
            if (have && g < kth && g + eq >= kth) {
                r_val  = myv;
                r_take = kth - g;   // how many ==T values belong to top-K
                r_ceq  = eq;        // total ==T values
            }
            barrier_nd();
            T       = (b1 << 21) | r_val;
            take_eq = r_take;
            c_eq    = r_ceq;
        } else {
            // ======== Rare fallback: radix rounds 2+3 (single hist copy) ========
            const bool use_cand = (cnt1 <= (unsigned)CAP);

            ((uint4*)hist)[tid] = make_uint4(0u, 0u, 0u, 0u);   // first 2048 bins
            barrier_nd();
            if (use_cand) {
                for (int i = tid; i < (int)cnt1; i += THREADS)
                    atomicAdd(&hist[cand[i] >> 10], 1u);
            } else {
#pragma unroll
                for (int e = 0; e < EPT; ++e)
                    if ((key[e] >> 21) == b1)
                        atomicAdd(&hist[(key[e] >> 10) & 0x7FFu], 1u);
            }
            barrier_nd();

            SELECT_BIN(4, 0)
            const unsigned b2 = sel_bin;
            kth = sel_kth;
            barrier_nd();

            if (tid < 256) ((uint4*)hist)[tid] = make_uint4(0u, 0u, 0u, 0u); // 1024 bins
            barrier_nd();
            if (use_cand) {
                for (int i = tid; i < (int)cnt1; i += THREADS) {
                    unsigned cv = cand[i];
                    if ((cv >> 10) == b2) atomicAdd(&hist[cv & 0x3FFu], 1u);
                }
            } else {
                const unsigned pfx = (b1 << 11) | b2;
#pragma unroll
                for (int e = 0; e < EPT; ++e)
                    if ((key[e] >> 10) == pfx)
                        atomicAdd(&hist[key[e] & 0x3FFu], 1u);
            }
            barrier_nd();

            SELECT_BIN(2, 0)
            T       = (b1 << 21) | (b2 << 10) | sel_bin;
            take_eq = sel_kth;
            c_eq    = sel_cnt;
        }

        const bool fast = (take_eq == c_eq);    // no boundary-straddling tie

        // ---- Write one-hot output from registers (non-temporal) ----
        f32x4* orow = (f32x4*)(out + row * (long long)N);
#pragma unroll
        for (int i = 0; i < VEC; ++i) {
            int idx = tid + i * THREADS;
            f32x4 o;
            o.x = (key[4*i+0] > T || (fast && key[4*i+0] == T)) ? 1.0f : 0.0f;
            o.y = (key[4*i+1] > T || (fast && key[4*i+1] == T)) ? 1.0f : 0.0f;
            o.z = (key[4*i+2] > T || (fast && key[4*i+2] == T)) ? 1.0f : 0.0f;
            o.w = (key[4*i+3] > T || (fast && key[4*i+3] == T)) ? 1.0f : 0.0f;
            __builtin_nontemporal_store(o, &orow[idx]);
        }

        // Rare path: tie group straddles the boundary — lowest indices win
        // (jax.lax.top_k semantics). Recompute serially from global.
        if (!fast) {
            __syncthreads();   // full drain: one-hot stores done before rewrite
            if (tid == 0) {
                const float* lf = logits + row * (long long)N;
                const float* nf = noise  + row * (long long)N;
                float* of = out + row * (long long)N;
                unsigned c = 0;
                for (int i = 0; i < N; ++i) {
                    if (orderable(lf[i] + nf[i]) == T) {
                        of[i] = 1.0f;
                        if (++c == take_eq) break;
                    }
                }
            }
        }
    }
#undef SELECT_BIN
}

extern "C" void kernel_launch(void* const* d_in, const int* in_sizes, int n_in,
                              void* d_out, int out_size, void* d_ws, size_t ws_size,
                              hipStream_t stream) {
    const float* logits = (const float*)d_in[0];
    const float* noise  = (const float*)d_in[1];
    float* out = (float*)d_out;
    const int rows = in_sizes[0] / N;           // 2048
    gumbel_topk_onehot<<<rows / RPB, THREADS, 0, stream>>>(logits, noise, out);
}

// Round 4
// 177.196 us; speedup vs baseline: 1.1325x; 1.0130x over previous
//
#include <hip/hip_runtime.h>

// Problem constants (fixed by the reference's setup_inputs).
constexpr int N = 8192;          // row length
constexpr int K = 64;            // top-k
constexpr int THREADS = 512;     // 8 waves/block, grid 2048 -> 4+ blocks/CU
constexpr int WAVES = THREADS / 64;
constexpr int EPT = N / THREADS; // 16 elements per thread (in registers)
constexpr int VEC = EPT / 4;     // 4 float4 loads per thread per operand
constexpr int CAP = 1024;        // candidate buffer capacity (4 KB)

// Pre-filter threshold: orderable(4.0f). For N(0,1)+Gumbel rows of 8192,
// count(x >= 4.0) ~ 247 +- 15.5 -> always in [K, 512] for this data.
// Rows violating that take the exact full-radix fallback below.
constexpr unsigned THRESH = 0xC0800000u;

typedef float f32x4 __attribute__((ext_vector_type(4)));

// Map fp32 bits to an unsigned key with the same total order as float.
__device__ __forceinline__ unsigned orderable(float f) {
    unsigned x = __float_as_uint(f);
    return (x & 0x80000000u) ? ~x : (x | 0x80000000u);
}

// Barrier that does NOT drain vmcnt (LDS-communication barriers only).
__device__ __forceinline__ void barrier_nd() {
    asm volatile("s_waitcnt lgkmcnt(0)" ::: "memory");
    __builtin_amdgcn_s_barrier();
    asm volatile("" ::: "memory");
}

__global__ __launch_bounds__(THREADS, 8)
void gumbel_topk_onehot(const float* __restrict__ logits,
                        const float* __restrict__ noise,
                        float* __restrict__ out)
{
    __shared__ __align__(16) unsigned hist[2048];   // 8 KB (fallback only)
    __shared__ __align__(16) unsigned cand[CAP];    // 4 KB: full keys of qualifiers
    __shared__ unsigned wavesum[WAVES];
    __shared__ unsigned ccount;
    __shared__ unsigned sel_bin, sel_kth, sel_cnt;
    __shared__ unsigned r_val, r_take, r_ceq;

    const int tid  = threadIdx.x;
    const int lane = tid & 63;
    const int wave = tid >> 6;
    const long long row = blockIdx.x;

    if (tid == 0) ccount = 0u;
    barrier_nd();                       // ccount=0 visible before any atomics

    // ---- Load row (all 8 float4 issued before any consumption) ----
    const float4* lrow = (const float4*)(logits + row * (long long)N);
    const float4* nrow = (const float4*)(noise  + row * (long long)N);
    float4 av[VEC], bv[VEC];
#pragma unroll
    for (int i = 0; i < VEC; ++i) av[i] = lrow[tid + i * THREADS];
#pragma unroll
    for (int i = 0; i < VEC; ++i) bv[i] = nrow[tid + i * THREADS];

    unsigned key[EPT];
#pragma unroll
    for (int i = 0; i < VEC; ++i) {
        key[4*i+0] = orderable(av[i].x + bv[i].x);
        key[4*i+1] = orderable(av[i].y + bv[i].y);
        key[4*i+2] = orderable(av[i].z + bv[i].z);
        key[4*i+3] = orderable(av[i].w + bv[i].w);
    }

    // ---- Ballot-aggregated compaction of qualifiers (key >= THRESH) ----
    // ~250 qualifiers/row -> ~16 wave-leader LDS atomics per wave total.
#pragma unroll
    for (int e = 0; e < EPT; ++e) {
        const bool p = (key[e] >= THRESH);
        unsigned long long mask = __ballot(p);
        if (mask) {                                     // wave-uniform
            const unsigned cnt   = (unsigned)__popcll(mask);
            const int      leader = __ffsll((long long)mask) - 1;
            unsigned base = 0;
            if (lane == leader) base = atomicAdd(&ccount, cnt);
            base = __shfl(base, leader);
            if (p) {
                unsigned off = (unsigned)__popcll(mask & ((1ull << lane) - 1ull));
                unsigned pos = base + off;
                if (pos < (unsigned)CAP) cand[pos] = key[e];
            }
        }
    }
    barrier_nd();                       // cand[] + ccount complete

    const unsigned c = ccount;
    unsigned T, take_eq, c_eq;

    if (c >= (unsigned)K && c <= (unsigned)THREADS) {
        // ======== Common path: exact rank-count among the c candidates ========
        // All elements below THRESH are smaller than every candidate, so the
        // K-th largest overall is the K-th largest candidate (c >= K).
        const bool have = (tid < (int)c);
        const unsigned myv = have ? cand[tid] : 0u;
        unsigned g = 0, eq = 0;
        if (tid < (int)((c + 63u) & ~63u)) {            // idle waves skip (uniform)
            int j = 0;
            for (; j + 4 <= (int)c; j += 4) {
                uint4 v = ((const uint4*)cand)[j >> 2]; // 16B broadcast read
                g  += (v.x >  myv) + (v.y >  myv) + (v.z >  myv) + (v.w >  myv);
                eq += (v.x == myv) + (v.y == myv) + (v.z == myv) + (v.w == myv);
            }
            for (; j < (int)c; ++j) {
                unsigned v = cand[j];
                g += (v > myv); eq += (v == myv);
            }
        }
        // The K-th largest value is the (unique) value with g < K <= g+eq.
        // All threads holding it write identical results (benign race).
        if (have && g < (unsigned)K && g + eq >= (unsigned)K) {
            r_val  = myv;
            r_take = (unsigned)K - g;   // how many ==T values belong to top-K
            r_ceq  = eq;                // total ==T values
        }
        barrier_nd();
        T       = r_val;
        take_eq = r_take;
        c_eq    = r_ceq;
    } else {
        // ======== Rare fallback: exact 3-round radix select (any input) ========
        unsigned kth = K;

#define SELECT_BIN(BPT)                                                      \
        {                                                                    \
            unsigned p = 0;                                                  \
            _Pragma("unroll")                                                \
            for (int j = 0; j < (BPT); ++j) p += hist[tid * (BPT) + j];      \
            unsigned s = p;                                                  \
            _Pragma("unroll")                                                \
            for (int off = 1; off < 64; off <<= 1) {                         \
                unsigned v = __shfl_down(s, off);                            \
                if (lane + off < 64) s += v;                                 \
            }                                                                \
            if (lane == 0) wavesum[wave] = s;                                \
            __syncthreads();                                                 \
            unsigned S = s;                                                  \
            _Pragma("unroll")                                                \
            for (int w = 0; w < WAVES; ++w) if (w > wave) S += wavesum[w];   \
            unsigned Snext = S - p;                                          \
            if (S >= kth && Snext < kth) {                                   \
                unsigned cum = Snext;                                        \
                for (int j = (BPT) - 1; j >= 0; --j) {                       \
                    unsigned b = tid * (BPT) + j;                            \
                    unsigned cc = hist[b];                                   \
                    if (cum + cc >= kth) {                                   \
                        sel_bin = b;                                         \
                        sel_kth = kth - cum;                                 \
                        sel_cnt = cc;                                        \
                        break;                                               \
                    }                                                        \
                    cum += cc;                                               \
                }                                                            \
            }                                                                \
            __syncthreads();                                                 \
        }

        // Round 1: bits [31:21]
        ((uint4*)hist)[tid] = make_uint4(0u, 0u, 0u, 0u);
        if (tid == 0) ccount = 0u;
        __syncthreads();
#pragma unroll
        for (int e = 0; e < EPT; ++e)
            atomicAdd(&hist[key[e] >> 21], 1u);
        __syncthreads();
        SELECT_BIN(4)
        const unsigned b1   = sel_bin;
        const unsigned cnt1 = sel_cnt;
        kth = sel_kth;

        // Compact round-1 survivors (low 21 bits)
#pragma unroll
        for (int e = 0; e < EPT; ++e) {
            if ((key[e] >> 21) == b1) {
                unsigned pos = atomicAdd(&ccount, 1u);
                if (pos < (unsigned)CAP) cand[pos] = key[e] & 0x1FFFFFu;
            }
        }
        __syncthreads();
        const bool use_cand = (cnt1 <= (unsigned)CAP);

        // Round 2: bits [20:10]
        ((uint4*)hist)[tid] = make_uint4(0u, 0u, 0u, 0u);
        __syncthreads();
        if (use_cand) {
            for (int i = tid; i < (int)cnt1; i += THREADS)
                atomicAdd(&hist[cand[i] >> 10], 1u);
        } else {
#pragma unroll
            for (int e = 0; e < EPT; ++e)
                if ((key[e] >> 21) == b1)
                    atomicAdd(&hist[(key[e] >> 10) & 0x7FFu], 1u);
        }
        __syncthreads();
        SELECT_BIN(4)
        const unsigned b2 = sel_bin;
        kth = sel_kth;
        __syncthreads();

        // Round 3: bits [9:0]
        if (tid < 256) ((uint4*)hist)[tid] = make_uint4(0u, 0u, 0u, 0u);
        __syncthreads();
        if (use_cand) {
            for (int i = tid; i < (int)cnt1; i += THREADS) {
                unsigned cv = cand[i];
                if ((cv >> 10) == b2) atomicAdd(&hist[cv & 0x3FFu], 1u);
            }
        } else {
            const unsigned pfx = (b1 << 11) | b2;
#pragma unroll
            for (int e = 0; e < EPT; ++e)
                if ((key[e] >> 10) == pfx)
                    atomicAdd(&hist[key[e] & 0x3FFu], 1u);
        }
        __syncthreads();
        SELECT_BIN(2)
        T       = (b1 << 21) | (b2 << 10) | sel_bin;
        take_eq = sel_kth;
        c_eq    = sel_cnt;
#undef SELECT_BIN
    }

    const bool fast = (take_eq == c_eq);    // no boundary-straddling tie

    // ---- Write one-hot output from registers (non-temporal) ----
    f32x4* orow = (f32x4*)(out + row * (long long)N);
#pragma unroll
    for (int i = 0; i < VEC; ++i) {
        int idx = tid + i * THREADS;
        f32x4 o;
        o.x = (key[4*i+0] > T || (fast && key[4*i+0] == T)) ? 1.0f : 0.0f;
        o.y = (key[4*i+1] > T || (fast && key[4*i+1] == T)) ? 1.0f : 0.0f;
        o.z = (key[4*i+2] > T || (fast && key[4*i+2] == T)) ? 1.0f : 0.0f;
        o.w = (key[4*i+3] > T || (fast && key[4*i+3] == T)) ? 1.0f : 0.0f;
        __builtin_nontemporal_store(o, &orow[idx]);
    }

    // Rare path: tie group straddles the boundary — lowest indices win
    // (jax.lax.top_k semantics). Recompute serially from global.
    if (!fast) {
        __syncthreads();   // full drain: one-hot stores done before rewrite
        if (tid == 0) {
            const float* lf = logits + row * (long long)N;
            const float* nf = noise  + row * (long long)N;
            float* of = out + row * (long long)N;
            unsigned cc = 0;
            for (int i = 0; i < N; ++i) {
                if (orderable(lf[i] + nf[i]) == T) {
                    of[i] = 1.0f;
                    if (++cc == take_eq) break;
                }
            }
        }
    }
}

extern "C" void kernel_launch(void* const* d_in, const int* in_sizes, int n_in,
                              void* d_out, int out_size, void* d_ws, size_t ws_size,
                              hipStream_t stream) {
    const float* logits = (const float*)d_in[0];
    const float* noise  = (const float*)d_in[1];
    float* out = (float*)d_out;
    const int rows = in_sizes[0] / N;   // 2048
    gumbel_topk_onehot<<<rows, THREADS, 0, stream>>>(logits, noise, out);
}

// Round 5
// 171.911 us; speedup vs baseline: 1.1673x; 1.0307x over previous
//
#include <hip/hip_runtime.h>

// Problem constants (fixed by the reference's setup_inputs).
constexpr int N = 8192;          // row length
constexpr int K = 64;            // top-k
constexpr int THREADS = 512;     // 8 waves/block, grid 2048
constexpr int WAVES = THREADS / 64;
constexpr int EPT = N / THREADS; // 16 elements per thread (in registers)
constexpr int VEC = EPT / 4;     // 4 float4 loads per thread per operand
constexpr int CAP = 1024;        // candidate buffer capacity (4 KB)

// Pre-filter threshold. For N(0,1)+Gumbel rows of 8192:
// E[count(x >= t)] = 8192 * e^(0.5 - t); at t=4.75 -> 117 +- 10.8.
// P(count < 64) ~ 5e-7 per row. Rows outside [K, 512] take the exact
// full-radix fallback, so this is a speed hint, not a correctness assumption.
constexpr float FTHRESH = 4.75f;

typedef float f32x4 __attribute__((ext_vector_type(4)));

// Map fp32 bits to an unsigned key with the same total order as float
// (fallback path only).
__device__ __forceinline__ unsigned orderable(float f) {
    unsigned x = __float_as_uint(f);
    return (x & 0x80000000u) ? ~x : (x | 0x80000000u);
}

// Barrier that does NOT drain vmcnt (LDS-communication barriers only).
__device__ __forceinline__ void barrier_nd() {
    asm volatile("s_waitcnt lgkmcnt(0)" ::: "memory");
    __builtin_amdgcn_s_barrier();
    asm volatile("" ::: "memory");
}

__global__ __launch_bounds__(THREADS, 8)
void gumbel_topk_onehot(const float* __restrict__ logits,
                        const float* __restrict__ noise,
                        float* __restrict__ out)
{
    __shared__ __align__(16) unsigned hist[2048];   // 8 KB (fallback only)
    __shared__ __align__(16) unsigned cand[CAP];    // 4 KB
    __shared__ unsigned wavesum[WAVES];
    __shared__ unsigned ccount;
    __shared__ unsigned sel_bin, sel_kth, sel_cnt;
    __shared__ unsigned r_val, r_take, r_ceq;

    const int tid  = threadIdx.x;
    const int lane = tid & 63;
    const int wave = tid >> 6;
    const long long row = blockIdx.x;

    if (tid == 0) ccount = 0u;

    // ---- Load row (all 8 float4 issued before any consumption) ----
    const float4* lrow = (const float4*)(logits + row * (long long)N);
    const float4* nrow = (const float4*)(noise  + row * (long long)N);
    float4 av[VEC], bv[VEC];
#pragma unroll
    for (int i = 0; i < VEC; ++i) av[i] = lrow[tid + i * THREADS];
#pragma unroll
    for (int i = 0; i < VEC; ++i) bv[i] = nrow[tid + i * THREADS];

    float s[EPT];
#pragma unroll
    for (int i = 0; i < VEC; ++i) {
        s[4*i+0] = av[i].x + bv[i].x;
        s[4*i+1] = av[i].y + bv[i].y;
        s[4*i+2] = av[i].z + bv[i].z;
        s[4*i+3] = av[i].w + bv[i].w;
    }
    barrier_nd();                       // ccount=0 visible (overlapped load flight)

    // ---- Sparse compaction of qualifiers (s >= FTHRESH), ~117/row ----
    // Plain predicated atomicAdd: LLVM's atomic optimizer lowers this to
    // ballot + mbcnt + one atomic per wave — aggregation for free.
#pragma unroll
    for (int e = 0; e < EPT; ++e) {
        if (s[e] >= FTHRESH) {
            unsigned pos = atomicAdd(&ccount, 1u);
            if (pos < (unsigned)CAP) cand[pos] = __float_as_uint(s[e]);
        }
    }
    barrier_nd();                       // cand[] + ccount complete

    const unsigned c = ccount;
    float Tf;                           // K-th largest value (as float)
    unsigned take_eq, c_eq;

    if (c >= (unsigned)K && c <= (unsigned)THREADS) {
        // ======== Common path: exact rank-count among the c candidates ========
        // All candidates are positive floats -> uint bit compare == float
        // compare. Elements below FTHRESH are smaller than every candidate.
        const bool have = (tid < (int)c);
        const unsigned myv = have ? cand[tid] : 0u;
        if (tid < (int)((c + 63u) & ~63u)) {            // idle waves -> barrier
            unsigned g = 0, eq = 0;
            int j = 0;
            for (; j + 4 <= (int)c; j += 4) {
                uint4 v = ((const uint4*)cand)[j >> 2]; // 16B broadcast read
                g  += (v.x >  myv) + (v.y >  myv) + (v.z >  myv) + (v.w >  myv);
                eq += (v.x == myv) + (v.y == myv) + (v.z == myv) + (v.w == myv);
            }
            for (; j < (int)c; ++j) {
                unsigned v = cand[j];
                g += (v > myv); eq += (v == myv);
            }
            // K-th largest = unique value with g < K <= g+eq. All threads
            // holding it write identical results (benign race).
            if (have && g < (unsigned)K && g + eq >= (unsigned)K) {
                r_val  = myv;
                r_take = (unsigned)K - g;
                r_ceq  = eq;
            }
        }
        barrier_nd();
        Tf      = __uint_as_float(r_val);
        take_eq = r_take;
        c_eq    = r_ceq;
    } else {
        // ======== Rare fallback: exact 3-round radix select (any input) ========
        unsigned kth = K;

#define SELECT_BIN(BPT)                                                      \
        {                                                                    \
            unsigned p = 0;                                                  \
            _Pragma("unroll")                                                \
            for (int j = 0; j < (BPT); ++j) p += hist[tid * (BPT) + j];      \
            unsigned sc = p;                                                 \
            _Pragma("unroll")                                                \
            for (int off = 1; off < 64; off <<= 1) {                         \
                unsigned v = __shfl_down(sc, off);                           \
                if (lane + off < 64) sc += v;                                \
            }                                                                \
            if (lane == 0) wavesum[wave] = sc;                               \
            __syncthreads();                                                 \
            unsigned S = sc;                                                 \
            _Pragma("unroll")                                                \
            for (int w = 0; w < WAVES; ++w) if (w > wave) S += wavesum[w];   \
            unsigned Snext = S - p;                                          \
            if (S >= kth && Snext < kth) {                                   \
                unsigned cum = Snext;                                        \
                for (int j = (BPT) - 1; j >= 0; --j) {                       \
                    unsigned b = tid * (BPT) + j;                            \
                    unsigned cc = hist[b];                                   \
                    if (cum + cc >= kth) {                                   \
                        sel_bin = b;                                         \
                        sel_kth = kth - cum;                                 \
                        sel_cnt = cc;                                        \
                        break;                                               \
                    }                                                        \
                    cum += cc;                                               \
                }                                                            \
            }                                                                \
            __syncthreads();                                                 \
        }

        // Round 1: bits [31:21] of orderable keys
        ((uint4*)hist)[tid] = make_uint4(0u, 0u, 0u, 0u);
        if (tid == 0) ccount = 0u;
        __syncthreads();
#pragma unroll
        for (int e = 0; e < EPT; ++e)
            atomicAdd(&hist[orderable(s[e]) >> 21], 1u);
        __syncthreads();
        SELECT_BIN(4)
        const unsigned b1   = sel_bin;
        const unsigned cnt1 = sel_cnt;
        kth = sel_kth;

        // Compact round-1 survivors (low 21 bits)
#pragma unroll
        for (int e = 0; e < EPT; ++e) {
            unsigned k_e = orderable(s[e]);
            if ((k_e >> 21) == b1) {
                unsigned pos = atomicAdd(&ccount, 1u);
                if (pos < (unsigned)CAP) cand[pos] = k_e & 0x1FFFFFu;
            }
        }
        __syncthreads();
        const bool use_cand = (cnt1 <= (unsigned)CAP);

        // Round 2: bits [20:10]
        ((uint4*)hist)[tid] = make_uint4(0u, 0u, 0u, 0u);
        __syncthreads();
        if (use_cand) {
            for (int i = tid; i < (int)cnt1; i += THREADS)
                atomicAdd(&hist[cand[i] >> 10], 1u);
        } else {
#pragma unroll
            for (int e = 0; e < EPT; ++e) {
                unsigned k_e = orderable(s[e]);
                if ((k_e >> 21) == b1)
                    atomicAdd(&hist[(k_e >> 10) & 0x7FFu], 1u);
            }
        }
        __syncthreads();
        SELECT_BIN(4)
        const unsigned b2 = sel_bin;
        kth = sel_kth;
        __syncthreads();

        // Round 3: bits [9:0]
        if (tid < 256) ((uint4*)hist)[tid] = make_uint4(0u, 0u, 0u, 0u);
        __syncthreads();
        if (use_cand) {
            for (int i = tid; i < (int)cnt1; i += THREADS) {
                unsigned cv = cand[i];
                if ((cv >> 10) == b2) atomicAdd(&hist[cv & 0x3FFu], 1u);
            }
        } else {
            const unsigned pfx = (b1 << 11) | b2;
#pragma unroll
            for (int e = 0; e < EPT; ++e) {
                unsigned k_e = orderable(s[e]);
                if ((k_e >> 10) == pfx)
                    atomicAdd(&hist[k_e & 0x3FFu], 1u);
            }
        }
        __syncthreads();
        SELECT_BIN(2)
        const unsigned T_ord = (b1 << 21) | (b2 << 10) | sel_bin;
        // Invert orderable(): high bit set -> nonnegative float, else negative.
        const unsigned bits = (T_ord & 0x80000000u) ? (T_ord & 0x7FFFFFFFu)
                                                    : ~T_ord;
        Tf      = __uint_as_float(bits);
        take_eq = sel_kth;
        c_eq    = sel_cnt;
#undef SELECT_BIN
    }

    const bool fast = (take_eq == c_eq);    // no boundary-straddling tie

    // ---- Write one-hot output from registers (non-temporal) ----
    // fast: top-K = { s >= Tf }.  !fast: { s > Tf } now, ties fixed below.
    f32x4* orow = (f32x4*)(out + row * (long long)N);
    if (fast) {
#pragma unroll
        for (int i = 0; i < VEC; ++i) {
            f32x4 o;
            o.x = (s[4*i+0] >= Tf) ? 1.0f : 0.0f;
            o.y = (s[4*i+1] >= Tf) ? 1.0f : 0.0f;
            o.z = (s[4*i+2] >= Tf) ? 1.0f : 0.0f;
            o.w = (s[4*i+3] >= Tf) ? 1.0f : 0.0f;
            __builtin_nontemporal_store(o, &orow[tid + i * THREADS]);
        }
    } else {
#pragma unroll
        for (int i = 0; i < VEC; ++i) {
            f32x4 o;
            o.x = (s[4*i+0] > Tf) ? 1.0f : 0.0f;
            o.y = (s[4*i+1] > Tf) ? 1.0f : 0.0f;
            o.z = (s[4*i+2] > Tf) ? 1.0f : 0.0f;
            o.w = (s[4*i+3] > Tf) ? 1.0f : 0.0f;
            __builtin_nontemporal_store(o, &orow[tid + i * THREADS]);
        }
        // Tie group straddles the boundary — lowest indices win
        // (jax.lax.top_k semantics). Recompute serially from global.
        __syncthreads();   // full drain: one-hot stores done before rewrite
        if (tid == 0) {
            const float* lf = logits + row * (long long)N;
            const float* nf = noise  + row * (long long)N;
            float* of = out + row * (long long)N;
            unsigned cc = 0;
            for (int i = 0; i < N; ++i) {
                if (lf[i] + nf[i] == Tf) {
                    of[i] = 1.0f;
                    if (++cc == take_eq) break;
                }
            }
        }
    }
}

extern "C" void kernel_launch(void* const* d_in, const int* in_sizes, int n_in,
                              void* d_out, int out_size, void* d_ws, size_t ws_size,
                              hipStream_t stream) {
    const float* logits = (const float*)d_in[0];
    const float* noise  = (const float*)d_in[1];
    float* out = (float*)d_out;
    const int rows = in_sizes[0] / N;   // 2048
    gumbel_topk_onehot<<<rows, THREADS, 0, stream>>>(logits, noise, out);
}